// Round 1
// 2086.261 us; speedup vs baseline: 1.0798x; 1.0798x over previous
//
#include <hip/hip_runtime.h>
#include <cstdint>
#include <cstddef>

#define IN_DIM 512
#define HID 2048
#define TOPK 50
#define MARGIN 4e-5f

typedef __attribute__((ext_vector_type(8))) short short8;
typedef __attribute__((ext_vector_type(4))) float f32x4;

__device__ __forceinline__ unsigned short f2bf(float f) {
  unsigned b = __float_as_uint(f);
  b += 0x7fffu + ((b >> 16) & 1u);          // round-to-nearest-even
  return (unsigned short)(b >> 16);
}
__device__ __forceinline__ float bf2f(unsigned short u) {
  return __uint_as_float(((unsigned)u) << 16);
}
__device__ __forceinline__ unsigned f2code(float f) {
  const unsigned b = __float_as_uint(f);
  return (b & 0x80000000u) ? ~b : (b | 0x80000000u);   // order-preserving
}
__device__ __forceinline__ float code2f(unsigned t) {
  return __uint_as_float((t & 0x80000000u) ? (t & 0x7fffffffu) : ~t);
}
__device__ __forceinline__ void dma16(const void* g, void* l) {
  __builtin_amdgcn_global_load_lds(
      (const __attribute__((address_space(1))) void*)g,
      (__attribute__((address_space(3))) void*)l, 16, 0, 0);
}
__device__ __forceinline__ int wave_sum(int c) {
#pragma unroll
  for (int s = 32; s > 0; s >>= 1) c += __shfl_xor(c, s, 64);
  return c;
}
__device__ __forceinline__ unsigned wave_max_u(unsigned m) {
#pragma unroll
  for (int s = 32; s > 0; s >>= 1) {
    const unsigned o = __shfl_xor(m, s, 64);
    m = o > m ? o : m;
  }
  return m;
}

// ---------------------------------------------------------------------------
// K0: transpose W_dec (512 x 2048) -> W_dec_T (2048 x 512)
// ---------------------------------------------------------------------------
__global__ __launch_bounds__(256) void transpose_wdec_kernel(
    const float* __restrict__ Wd, float* __restrict__ WdT)
{
  __shared__ float tile[32][33];
  const int bx = blockIdx.x & 63;
  const int by = blockIdx.x >> 6;
  const int tx = threadIdx.x & 31;
  const int ty = threadIdx.x >> 5;
#pragma unroll
  for (int i = 0; i < 4; ++i)
    tile[ty + i * 8][tx] = Wd[(size_t)(by * 32 + ty + i * 8) * HID + bx * 32 + tx];
  __syncthreads();
#pragma unroll
  for (int i = 0; i < 4; ++i)
    WdT[(size_t)(bx * 32 + ty + i * 8) * IN_DIM + by * 32 + tx] = tile[tx][ty + i * 8];
}

// ---------------------------------------------------------------------------
// K1a: split W_enc (2048x512 fp32) -> WeHi, WeLo (bf16 as ushort)
// ---------------------------------------------------------------------------
__global__ __launch_bounds__(256) void split_we_kernel(
    const float* __restrict__ We, unsigned short* __restrict__ wh,
    unsigned short* __restrict__ wl)
{
  const int i4 = blockIdx.x * 256 + threadIdx.x;   // HID*IN_DIM/4 total
  const float4 v = ((const float4*)We)[i4];
  ushort4 h, l;
  h.x = f2bf(v.x); l.x = f2bf(v.x - bf2f(h.x));
  h.y = f2bf(v.y); l.y = f2bf(v.y - bf2f(h.y));
  h.z = f2bf(v.z); l.z = f2bf(v.z - bf2f(h.z));
  h.w = f2bf(v.w); l.w = f2bf(v.w - bf2f(h.w));
  ((ushort4*)wh)[i4] = h;
  ((ushort4*)wl)[i4] = l;
}

// ---------------------------------------------------------------------------
// K1b: xc = x - (b_dec + pre_bias); split -> xcHi, xcLo (stored in recon area)
// ---------------------------------------------------------------------------
__global__ __launch_bounds__(256) void split_x_kernel(
    const float* __restrict__ x, const float* __restrict__ bd,
    const float* __restrict__ pb, unsigned short* __restrict__ xh,
    unsigned short* __restrict__ xl)
{
  const int i4 = blockIdx.x * 256 + threadIdx.x;   // M*IN_DIM/4 total
  const int k4 = (i4 & 127) * 4;
  const float4 v = ((const float4*)x)[i4];
  const float4 b = *(const float4*)(bd + k4);
  const float4 p = *(const float4*)(pb + k4);
  float c0 = v.x - (b.x + p.x);
  float c1 = v.y - (b.y + p.y);
  float c2 = v.z - (b.z + p.z);
  float c3 = v.w - (b.w + p.w);
  ushort4 h, l;
  h.x = f2bf(c0); l.x = f2bf(c0 - bf2f(h.x));
  h.y = f2bf(c1); l.y = f2bf(c1 - bf2f(h.y));
  h.z = f2bf(c2); l.z = f2bf(c2 - bf2f(h.z));
  h.w = f2bf(c3); l.w = f2bf(c3 - bf2f(h.w));
  ((ushort4*)xh)[i4] = h;
  ((ushort4*)xl)[i4] = l;
}

// ---------------------------------------------------------------------------
// K2: z = xc @ We^T + be  via bf16x3 MFMA (hi*hi + hi*lo + lo*hi).
// 128x128 tile, BK=32, 4 waves in 2x2 grid, wave tile 64x64 = 4x4 MFMA tiles.
// All operands DMA'd to LDS via global_load_lds width=16 (m97 structure).
// ---------------------------------------------------------------------------
__global__ __launch_bounds__(256) void enc_gemm_mfma_kernel(
    const unsigned short* __restrict__ xh, const unsigned short* __restrict__ xl,
    const unsigned short* __restrict__ wh, const unsigned short* __restrict__ wl,
    const float* __restrict__ be, float* __restrict__ z)
{
  __shared__ __align__(16) unsigned short sAh[128 * 32];
  __shared__ __align__(16) unsigned short sAl[128 * 32];
  __shared__ __align__(16) unsigned short sBh[128 * 32];
  __shared__ __align__(16) unsigned short sBl[128 * 32];

  const int tid = threadIdx.x;
  const int lane = tid & 63, wv = tid >> 6;
  const int wm = wv & 1, wn = wv >> 1;
  const size_t row0 = (size_t)(blockIdx.x >> 4) * 128;
  const int col0 = (blockIdx.x & 15) * 128;

  f32x4 acc[4][4];
#pragma unroll
  for (int i = 0; i < 4; ++i)
#pragma unroll
    for (int j = 0; j < 4; ++j) acc[i][j] = (f32x4){0.f, 0.f, 0.f, 0.f};

  // chunk c (16 B) -> logical (r = c>>2, k-quad = c&3); LDS image is linear.
  const int c0 = tid, c1 = tid + 256;
  const int r0 = c0 >> 2, kq0 = (c0 & 3) * 8;
  const int r1 = c1 >> 2, kq1 = (c1 & 3) * 8;
  const int lds0 = (wv * 64) * 8;          // elements; + implicit lane*16 B
  const int lds1 = (256 + wv * 64) * 8;

  const int fr = lane & 15, fq = (lane >> 4) * 8;

  for (int k0 = 0; k0 < IN_DIM; k0 += 32) {
    dma16(xh + (row0 + r0) * IN_DIM + k0 + kq0, sAh + lds0);
    dma16(xh + (row0 + r1) * IN_DIM + k0 + kq1, sAh + lds1);
    dma16(xl + (row0 + r0) * IN_DIM + k0 + kq0, sAl + lds0);
    dma16(xl + (row0 + r1) * IN_DIM + k0 + kq1, sAl + lds1);
    dma16(wh + (size_t)(col0 + r0) * IN_DIM + k0 + kq0, sBh + lds0);
    dma16(wh + (size_t)(col0 + r1) * IN_DIM + k0 + kq1, sBh + lds1);
    dma16(wl + (size_t)(col0 + r0) * IN_DIM + k0 + kq0, sBl + lds0);
    dma16(wl + (size_t)(col0 + r1) * IN_DIM + k0 + kq1, sBl + lds1);
    __syncthreads();

    short8 ah[4], al[4], bh[4], bl[4];
#pragma unroll
    for (int t = 0; t < 4; ++t) {
      ah[t] = *(const short8*)(sAh + (wm * 64 + t * 16 + fr) * 32 + fq);
      al[t] = *(const short8*)(sAl + (wm * 64 + t * 16 + fr) * 32 + fq);
      bh[t] = *(const short8*)(sBh + (wn * 64 + t * 16 + fr) * 32 + fq);
      bl[t] = *(const short8*)(sBl + (wn * 64 + t * 16 + fr) * 32 + fq);
    }
#pragma unroll
    for (int mt = 0; mt < 4; ++mt)
#pragma unroll
      for (int nt = 0; nt < 4; ++nt) {
        acc[mt][nt] = __builtin_amdgcn_mfma_f32_16x16x32_bf16(ah[mt], bh[nt], acc[mt][nt], 0, 0, 0);
        acc[mt][nt] = __builtin_amdgcn_mfma_f32_16x16x32_bf16(ah[mt], bl[nt], acc[mt][nt], 0, 0, 0);
        acc[mt][nt] = __builtin_amdgcn_mfma_f32_16x16x32_bf16(al[mt], bh[nt], acc[mt][nt], 0, 0, 0);
      }
    __syncthreads();
  }

  // epilogue: C/D layout col=lane&15, row=(lane>>4)*4+reg  [m89-verified]
  const int ccol = lane & 15, crow4 = (lane >> 4) * 4;
#pragma unroll
  for (int nt = 0; nt < 4; ++nt) {
    const int col = col0 + wn * 64 + nt * 16 + ccol;
    const float bias = be[col];
#pragma unroll
    for (int mt = 0; mt < 4; ++mt) {
      const size_t rb = row0 + wm * 64 + mt * 16 + crow4;
#pragma unroll
      for (int r = 0; r < 4; ++r)
        z[(rb + r) * HID + col] = acc[mt][nt][r] + bias;
    }
  }
}

// ---------------------------------------------------------------------------
// K3: per-row exact-rank threshold + sparsify + decode (fused).
// Selection rewritten (this round): instead of two full 32-bit binary
// searches (~4800 VALU ops/row), use:
//   (a) bitonic shuffle-sort of the 64 lane-maxima -> [L50, gmax] bounds
//       (L50 = 50th-largest lane max; provably count(u>=L50)>=50)
//   (b) binary search on the HIGH 16 BITS only, within those bounds
//       (expected ~6-7 iterations; h = T>>16 exactly)
//   (c) masked max-extraction with multiplicity to resolve ties in the
//       high half (expected 1-2 values)
//   (d) rank-51 for the MARGIN flag = max{u < T} (plus tied-at-T => gap 0)
// Threshold T is bit-identical to the previous binary-search fixpoint, so
// selection/flag/fixup semantics are unchanged.
// ---------------------------------------------------------------------------
__global__ __launch_bounds__(256) void topk_decode_kernel(
    float* __restrict__ z, const float* __restrict__ WdT,
    const float* __restrict__ bd, float* __restrict__ recon,
    int* __restrict__ flagCount, int* __restrict__ flagList)
{
  __shared__ float2 s_pair[4][64];
  const int w = threadIdx.x >> 6;
  const int lane = threadIdx.x & 63;
  const int row = blockIdx.x * 4 + w;
  float* zr = z + (size_t)row * HID;

  unsigned u[32], uh[32];
#pragma unroll
  for (int j2 = 0; j2 < 8; ++j2) {
    const float4 t = *(const float4*)(zr + j2 * 256 + lane * 4);
    u[j2 * 4 + 0] = f2code(t.x);
    u[j2 * 4 + 1] = f2code(t.y);
    u[j2 * 4 + 2] = f2code(t.z);
    u[j2 * 4 + 3] = f2code(t.w);
  }
#pragma unroll
  for (int j = 0; j < 32; ++j) uh[j] = u[j] >> 16;

  // ---- (a) lane max + bitonic sort of lane maxima across the wave ----
  unsigned lmax = u[0];
#pragma unroll
  for (int j = 1; j < 32; ++j) lmax = u[j] > lmax ? u[j] : lmax;

  unsigned sv = lmax;
#pragma unroll
  for (int k = 2; k <= 64; k <<= 1) {
#pragma unroll
    for (int j = k >> 1; j > 0; j >>= 1) {
      const unsigned other = __shfl_xor(sv, j, 64);
      const bool keepSmall = (((lane & j) == 0) == ((lane & k) == 0));
      const bool less = sv < other;
      sv = (keepSmall == less) ? sv : other;
    }
  }
  // ascending by lane: lane 63 = global max, lane 14 = 50th largest lane-max
  const unsigned L50  = __shfl(sv, 14, 64);
  const unsigned gmax = __shfl(sv, 63, 64);

  // ---- (b) binary search on high 16 bits: h = T >> 16 ----
  unsigned blo = L50 >> 16;          // count(uh >= blo) >= 50 guaranteed
  unsigned bhi = (gmax >> 16) + 1u;  // count(uh >= bhi) == 0
  while (bhi - blo > 1u) {
    const unsigned mid = blo + ((bhi - blo) >> 1);
    int c0 = 0, c1 = 0, c2 = 0, c3 = 0;
#pragma unroll
    for (int j = 0; j < 32; j += 4) {
      c0 += (uh[j + 0] >= mid) ? 1 : 0;
      c1 += (uh[j + 1] >= mid) ? 1 : 0;
      c2 += (uh[j + 2] >= mid) ? 1 : 0;
      c3 += (uh[j + 3] >= mid) ? 1 : 0;
    }
    const int c = wave_sum((c0 + c1) + (c2 + c3));
    if (c >= TOPK) blo = mid; else bhi = mid;
  }
  const unsigned h = blo;

  // rank of T inside the tied-high-half group
  int d0 = 0, d1 = 0, d2 = 0, d3 = 0;
#pragma unroll
  for (int j = 0; j < 32; j += 4) {
    d0 += (uh[j + 0] > h) ? 1 : 0;
    d1 += (uh[j + 1] > h) ? 1 : 0;
    d2 += (uh[j + 2] > h) ? 1 : 0;
    d3 += (uh[j + 3] > h) ? 1 : 0;
  }
  int r = TOPK - wave_sum((d0 + d1) + (d2 + d3));   // >= 1

  // ---- (c) extract r-th largest (with multiplicity) among {uh == h} ----
  unsigned cur = 0xFFFFFFFFu;
  while (r > 0) {
    unsigned cand = 0u;
#pragma unroll
    for (int j = 0; j < 32; ++j) {
      const unsigned x = ((uh[j] == h) && (u[j] < cur)) ? u[j] : 0u;
      cand = x > cand ? x : cand;
    }
    cand = wave_max_u(cand);
    int e0 = 0, e1 = 0;
#pragma unroll
    for (int j = 0; j < 32; j += 2) {
      e0 += (u[j + 0] == cand) ? 1 : 0;
      e1 += (u[j + 1] == cand) ? 1 : 0;
    }
    r -= wave_sum(e0 + e1);
    cur = cand;
  }
  const unsigned T = cur;

  // ---- (d) 51st value for the near-tie flag ----
  int t0 = 0, t1 = 0;
#pragma unroll
  for (int j = 0; j < 32; j += 2) {
    t0 += (u[j + 0] >= T) ? 1 : 0;
    t1 += (u[j + 1] >= T) ? 1 : 0;
  }
  const int cT = wave_sum(t0 + t1);
  unsigned below = 0u;
#pragma unroll
  for (int j = 0; j < 32; ++j) {
    const unsigned x = (u[j] < T) ? u[j] : 0u;
    below = x > below ? x : below;
  }
  below = wave_max_u(below);
  if (lane == 0) {
    const float gap = (cT > TOPK) ? 0.0f : (code2f(T) - code2f(below));
    if (gap < MARGIN) {
      const int idx = atomicAdd(flagCount, 1);
      flagList[idx] = row;
    }
  }

  // sparsify in place (code2f(f2code(v)) == v bitwise; exact reconstruction)
#pragma unroll
  for (int j2 = 0; j2 < 8; ++j2) {
    float4 o;
    o.x = (u[j2 * 4 + 0] >= T) ? code2f(u[j2 * 4 + 0]) : 0.0f;
    o.y = (u[j2 * 4 + 1] >= T) ? code2f(u[j2 * 4 + 1]) : 0.0f;
    o.z = (u[j2 * 4 + 2] >= T) ? code2f(u[j2 * 4 + 2]) : 0.0f;
    o.w = (u[j2 * 4 + 3] >= T) ? code2f(u[j2 * 4 + 3]) : 0.0f;
    *(float4*)(zr + j2 * 256 + lane * 4) = o;
  }

  // ballot-compact survivors
  s_pair[w][lane] = make_float2(0.0f, __int_as_float(0));
  int base = 0;
#pragma unroll
  for (int j = 0; j < 32; ++j) {
    const bool pass = (u[j] >= T);
    const unsigned long long mask = __ballot(pass);
    if (pass) {
      const int pos = base + __popcll(mask & ((1ull << lane) - 1ull));
      if (pos < 64) {
        const int hidx = (j >> 2) * 256 + lane * 4 + (j & 3);
        s_pair[w][pos] = make_float2(code2f(u[j]), __int_as_float(hidx));
      }
    }
    base += __popcll(mask);
  }
  const int cnt = (base < 64) ? base : 64;

  float acc[8];
  {
    const float4 b0 = *(const float4*)(bd + lane * 8);
    const float4 b1 = *(const float4*)(bd + lane * 8 + 4);
    acc[0] = b0.x; acc[1] = b0.y; acc[2] = b0.z; acc[3] = b0.w;
    acc[4] = b1.x; acc[5] = b1.y; acc[6] = b1.z; acc[7] = b1.w;
  }
  for (int i = 0; i < cnt; ++i) {
    const float2 p = s_pair[w][i];
    const float zv = p.x;
    const int hh = __float_as_int(p.y);
    const float* wr = WdT + (size_t)hh * IN_DIM + lane * 8;
    const float4 w0 = *(const float4*)wr;
    const float4 w1 = *(const float4*)(wr + 4);
    acc[0] += zv * w0.x; acc[1] += zv * w0.y;
    acc[2] += zv * w0.z; acc[3] += zv * w0.w;
    acc[4] += zv * w1.x; acc[5] += zv * w1.y;
    acc[6] += zv * w1.z; acc[7] += zv * w1.w;
  }

  float* rr = recon + (size_t)row * IN_DIM + lane * 8;
  float4 o0, o1;
  o0.x = acc[0]; o0.y = acc[1]; o0.z = acc[2]; o0.w = acc[3];
  o1.x = acc[4]; o1.y = acc[5]; o1.z = acc[6]; o1.w = acc[7];
  *(float4*)(rr) = o0;
  *(float4*)(rr + 4) = o1;
}

// ---------------------------------------------------------------------------
// K4: exact fixup for flagged rows — recompute z with sequential ascending
// fp32 FMA (the R1 semantics that matched the np reference), redo selection,
// rewrite z_sparse row and recon row. One wave (64-thread block) per row.
// ---------------------------------------------------------------------------
__global__ __launch_bounds__(64) void fixup_kernel(
    const float* __restrict__ x, const float* __restrict__ We,
    const float* __restrict__ be, const float* __restrict__ bd,
    const float* __restrict__ pb, const float* __restrict__ WdT,
    const int* __restrict__ flagCount, const int* __restrict__ flagList,
    float* __restrict__ z, float* __restrict__ recon)
{
  __shared__ float sxc[IN_DIM];
  __shared__ float2 spair[64];
  const int lane = threadIdx.x;
  const int nflag = *flagCount;

  for (int fi = blockIdx.x; fi < nflag; fi += gridDim.x) {
    const int row = flagList[fi];
#pragma unroll
    for (int t = 0; t < 8; ++t) {
      const int k = lane + t * 64;
      sxc[k] = x[(size_t)row * IN_DIM + k] - (bd[k] + pb[k]);
    }
    __syncthreads();

    float v[32];
    unsigned u[32];
#pragma unroll
    for (int j = 0; j < 32; ++j) {
      const int f = lane + 64 * j;
      const float* wr = We + (size_t)f * IN_DIM;
      float a = 0.f;
      for (int k4 = 0; k4 < IN_DIM; k4 += 4) {
        const float4 w4 = *(const float4*)(wr + k4);
        a = fmaf(sxc[k4 + 0], w4.x, a);
        a = fmaf(sxc[k4 + 1], w4.y, a);
        a = fmaf(sxc[k4 + 2], w4.z, a);
        a = fmaf(sxc[k4 + 3], w4.w, a);
      }
      v[j] = a + be[f];
      u[j] = f2code(v[j]);
    }

    unsigned lo = 0u, hi = 0xFFFFFFFFu;
    while (hi - lo > 1u) {
      const unsigned mid = lo + ((hi - lo) >> 1);
      int c = 0;
#pragma unroll
      for (int j = 0; j < 32; ++j) c += (u[j] >= mid) ? 1 : 0;
#pragma unroll
      for (int s = 32; s > 0; s >>= 1) c += __shfl_xor(c, s, 64);
      if (c >= TOPK) lo = mid; else hi = mid;
    }

    // rewrite z_sparse row
#pragma unroll
    for (int j = 0; j < 32; ++j)
      z[(size_t)row * HID + lane + 64 * j] = (u[j] >= lo) ? v[j] : 0.0f;

    // compact + recon
    spair[lane] = make_float2(0.0f, __int_as_float(0));
    __syncthreads();
    int base = 0;
#pragma unroll
    for (int j = 0; j < 32; ++j) {
      const bool pass = (u[j] >= lo);
      const unsigned long long mask = __ballot(pass);
      if (pass) {
        const int pos = base + __popcll(mask & ((1ull << lane) - 1ull));
        if (pos < 64) spair[pos] = make_float2(v[j], __int_as_float(lane + 64 * j));
      }
      base += __popcll(mask);
    }
    __syncthreads();
    const int cnt = (base < 64) ? base : 64;

    float acc[8];
    {
      const float4 b0 = *(const float4*)(bd + lane * 8);
      const float4 b1 = *(const float4*)(bd + lane * 8 + 4);
      acc[0] = b0.x; acc[1] = b0.y; acc[2] = b0.z; acc[3] = b0.w;
      acc[4] = b1.x; acc[5] = b1.y; acc[6] = b1.z; acc[7] = b1.w;
    }
    for (int i = 0; i < cnt; ++i) {
      const float2 p = spair[i];
      const float* wr = WdT + (size_t)__float_as_int(p.y) * IN_DIM + lane * 8;
      const float4 w0 = *(const float4*)wr;
      const float4 w1 = *(const float4*)(wr + 4);
      acc[0] += p.x * w0.x; acc[1] += p.x * w0.y;
      acc[2] += p.x * w0.z; acc[3] += p.x * w0.w;
      acc[4] += p.x * w1.x; acc[5] += p.x * w1.y;
      acc[6] += p.x * w1.z; acc[7] += p.x * w1.w;
    }
    float* rr = recon + (size_t)row * IN_DIM + lane * 8;
    *(float4*)(rr) = make_float4(acc[0], acc[1], acc[2], acc[3]);
    *(float4*)(rr + 4) = make_float4(acc[4], acc[5], acc[6], acc[7]);
    __syncthreads();
  }
}

// ---------------------------------------------------------------------------
extern "C" void kernel_launch(void* const* d_in, const int* in_sizes, int n_in,
                              void* d_out, int out_size, void* d_ws, size_t ws_size,
                              hipStream_t stream)
{
  const float* x  = (const float*)d_in[0];
  const float* We = (const float*)d_in[1];
  const float* be = (const float*)d_in[2];
  const float* Wd = (const float*)d_in[3];
  const float* bd = (const float*)d_in[4];
  const float* pb = (const float*)d_in[5];

  const int M = in_sizes[0] / IN_DIM;   // 65536

  float* recon = (float*)d_out;                        // M x 512
  float* zs    = (float*)d_out + (size_t)M * IN_DIM;   // M x 2048 (z -> z_sparse)
  // xcHi/xcLo live in the recon region (dead until topk_decode writes it)
  unsigned short* xcHi = (unsigned short*)recon;                    // M*512 u16
  unsigned short* xcLo = xcHi + (size_t)M * IN_DIM;                 // M*512 u16

  char* ws = (char*)d_ws;
  float* WdT           = (float*)ws;                    // 4 MB
  unsigned short* WeHi = (unsigned short*)(ws + (4 << 20));   // 2 MB
  unsigned short* WeLo = (unsigned short*)(ws + (6 << 20));   // 2 MB
  int* flagCount       = (int*)(ws + (8 << 20));
  int* flagList        = flagCount + 16;

  hipMemsetAsync(flagCount, 0, 64, stream);
  transpose_wdec_kernel<<<1024, 256, 0, stream>>>(Wd, WdT);
  split_we_kernel<<<(HID * IN_DIM / 4) / 256, 256, 0, stream>>>(We, WeHi, WeLo);
  split_x_kernel<<<(M * (IN_DIM / 4)) / 256, 256, 0, stream>>>(x, bd, pb, xcHi, xcLo);
  enc_gemm_mfma_kernel<<<(M / 128) * (HID / 128), 256, 0, stream>>>(
      xcHi, xcLo, WeHi, WeLo, be, zs);
  topk_decode_kernel<<<M / 4, 256, 0, stream>>>(zs, WdT, bd, recon, flagCount, flagList);
  fixup_kernel<<<2048, 64, 0, stream>>>(x, We, be, bd, pb, WdT,
                                        flagCount, flagList, zs, recon);
}

// Round 2
// 2049.875 us; speedup vs baseline: 1.0989x; 1.0178x over previous
//
#include <hip/hip_runtime.h>
#include <cstdint>
#include <cstddef>

#define IN_DIM 512
#define HID 2048
#define TOPK 50
#define MARGIN 4e-5f

typedef __attribute__((ext_vector_type(8))) short short8;
typedef __attribute__((ext_vector_type(4))) float f32x4;

__device__ __forceinline__ unsigned short f2bf(float f) {
  unsigned b = __float_as_uint(f);
  b += 0x7fffu + ((b >> 16) & 1u);          // round-to-nearest-even
  return (unsigned short)(b >> 16);
}
__device__ __forceinline__ float bf2f(unsigned short u) {
  return __uint_as_float(((unsigned)u) << 16);
}
__device__ __forceinline__ unsigned f2code(float f) {
  const unsigned b = __float_as_uint(f);
  return (b & 0x80000000u) ? ~b : (b | 0x80000000u);   // order-preserving
}
__device__ __forceinline__ float code2f(unsigned t) {
  return __uint_as_float((t & 0x80000000u) ? (t & 0x7fffffffu) : ~t);
}
__device__ __forceinline__ void dma16(const void* g, void* l) {
  __builtin_amdgcn_global_load_lds(
      (const __attribute__((address_space(1))) void*)g,
      (__attribute__((address_space(3))) void*)l, 16, 0, 0);
}
__device__ __forceinline__ unsigned wave_max_u(unsigned m) {
#pragma unroll
  for (int s = 32; s > 0; s >>= 1) {
    const unsigned o = __shfl_xor(m, s, 64);
    m = o > m ? o : m;
  }
  return m;
}

// ---------------------------------------------------------------------------
// K0: transpose W_dec (512 x 2048) -> W_dec_T (2048 x 512)
// ---------------------------------------------------------------------------
__global__ __launch_bounds__(256) void transpose_wdec_kernel(
    const float* __restrict__ Wd, float* __restrict__ WdT)
{
  __shared__ float tile[32][33];
  const int bx = blockIdx.x & 63;
  const int by = blockIdx.x >> 6;
  const int tx = threadIdx.x & 31;
  const int ty = threadIdx.x >> 5;
#pragma unroll
  for (int i = 0; i < 4; ++i)
    tile[ty + i * 8][tx] = Wd[(size_t)(by * 32 + ty + i * 8) * HID + bx * 32 + tx];
  __syncthreads();
#pragma unroll
  for (int i = 0; i < 4; ++i)
    WdT[(size_t)(bx * 32 + ty + i * 8) * IN_DIM + by * 32 + tx] = tile[tx][ty + i * 8];
}

// ---------------------------------------------------------------------------
// K1a: split W_enc (2048x512 fp32) -> WeHi, WeLo (bf16 as ushort)
// ---------------------------------------------------------------------------
__global__ __launch_bounds__(256) void split_we_kernel(
    const float* __restrict__ We, unsigned short* __restrict__ wh,
    unsigned short* __restrict__ wl)
{
  const int i4 = blockIdx.x * 256 + threadIdx.x;   // HID*IN_DIM/4 total
  const float4 v = ((const float4*)We)[i4];
  ushort4 h, l;
  h.x = f2bf(v.x); l.x = f2bf(v.x - bf2f(h.x));
  h.y = f2bf(v.y); l.y = f2bf(v.y - bf2f(h.y));
  h.z = f2bf(v.z); l.z = f2bf(v.z - bf2f(h.z));
  h.w = f2bf(v.w); l.w = f2bf(v.w - bf2f(h.w));
  ((ushort4*)wh)[i4] = h;
  ((ushort4*)wl)[i4] = l;
}

// ---------------------------------------------------------------------------
// K1b: xc = x - (b_dec + pre_bias); split -> xcHi, xcLo (stored in recon area)
// ---------------------------------------------------------------------------
__global__ __launch_bounds__(256) void split_x_kernel(
    const float* __restrict__ x, const float* __restrict__ bd,
    const float* __restrict__ pb, unsigned short* __restrict__ xh,
    unsigned short* __restrict__ xl)
{
  const int i4 = blockIdx.x * 256 + threadIdx.x;   // M*IN_DIM/4 total
  const int k4 = (i4 & 127) * 4;
  const float4 v = ((const float4*)x)[i4];
  const float4 b = *(const float4*)(bd + k4);
  const float4 p = *(const float4*)(pb + k4);
  float c0 = v.x - (b.x + p.x);
  float c1 = v.y - (b.y + p.y);
  float c2 = v.z - (b.z + p.z);
  float c3 = v.w - (b.w + p.w);
  ushort4 h, l;
  h.x = f2bf(c0); l.x = f2bf(c0 - bf2f(h.x));
  h.y = f2bf(c1); l.y = f2bf(c1 - bf2f(h.y));
  h.z = f2bf(c2); l.z = f2bf(c2 - bf2f(h.z));
  h.w = f2bf(c3); l.w = f2bf(c3 - bf2f(h.w));
  ((ushort4*)xh)[i4] = h;
  ((ushort4*)xl)[i4] = l;
}

// ---------------------------------------------------------------------------
// K2: z = xc @ We^T + be  via bf16x3 MFMA (hi*hi + hi*lo + lo*hi).
// 128x128 tile, BK=32, 4 waves in 2x2 grid, wave tile 64x64 = 4x4 MFMA tiles.
// All operands DMA'd to LDS via global_load_lds width=16 (m97 structure).
// This round: bijective XCD-chunk swizzle (gridDim % 8 == 0) so the 16
// col-blocks sharing one A-panel run on the same XCD (A-panel L2 reuse).
// ---------------------------------------------------------------------------
__global__ __launch_bounds__(256) void enc_gemm_mfma_kernel(
    const unsigned short* __restrict__ xh, const unsigned short* __restrict__ xl,
    const unsigned short* __restrict__ wh, const unsigned short* __restrict__ wl,
    const float* __restrict__ be, float* __restrict__ z)
{
  __shared__ __align__(16) unsigned short sAh[128 * 32];
  __shared__ __align__(16) unsigned short sAl[128 * 32];
  __shared__ __align__(16) unsigned short sBh[128 * 32];
  __shared__ __align__(16) unsigned short sBl[128 * 32];

  const int tid = threadIdx.x;
  const int lane = tid & 63, wv = tid >> 6;
  const int wm = wv & 1, wn = wv >> 1;

  // XCD-chunk swizzle: contiguous sb-range per XCD (bijective: nwg % 8 == 0)
  const int bid = blockIdx.x;
  const int cpx = (int)(gridDim.x >> 3);
  const int sb = (bid & 7) * cpx + (bid >> 3);
  const size_t row0 = (size_t)(sb >> 4) * 128;
  const int col0 = (sb & 15) * 128;

  f32x4 acc[4][4];
#pragma unroll
  for (int i = 0; i < 4; ++i)
#pragma unroll
    for (int j = 0; j < 4; ++j) acc[i][j] = (f32x4){0.f, 0.f, 0.f, 0.f};

  // chunk c (16 B) -> logical (r = c>>2, k-quad = c&3); LDS image is linear.
  const int c0 = tid, c1 = tid + 256;
  const int r0 = c0 >> 2, kq0 = (c0 & 3) * 8;
  const int r1 = c1 >> 2, kq1 = (c1 & 3) * 8;
  const int lds0 = (wv * 64) * 8;          // elements; + implicit lane*16 B
  const int lds1 = (256 + wv * 64) * 8;

  const int fr = lane & 15, fq = (lane >> 4) * 8;

  for (int k0 = 0; k0 < IN_DIM; k0 += 32) {
    dma16(xh + (row0 + r0) * IN_DIM + k0 + kq0, sAh + lds0);
    dma16(xh + (row0 + r1) * IN_DIM + k0 + kq1, sAh + lds1);
    dma16(xl + (row0 + r0) * IN_DIM + k0 + kq0, sAl + lds0);
    dma16(xl + (row0 + r1) * IN_DIM + k0 + kq1, sAl + lds1);
    dma16(wh + (size_t)(col0 + r0) * IN_DIM + k0 + kq0, sBh + lds0);
    dma16(wh + (size_t)(col0 + r1) * IN_DIM + k0 + kq1, sBh + lds1);
    dma16(wl + (size_t)(col0 + r0) * IN_DIM + k0 + kq0, sBl + lds0);
    dma16(wl + (size_t)(col0 + r1) * IN_DIM + k0 + kq1, sBl + lds1);
    __syncthreads();

    short8 ah[4], al[4], bh[4], bl[4];
#pragma unroll
    for (int t = 0; t < 4; ++t) {
      ah[t] = *(const short8*)(sAh + (wm * 64 + t * 16 + fr) * 32 + fq);
      al[t] = *(const short8*)(sAl + (wm * 64 + t * 16 + fr) * 32 + fq);
      bh[t] = *(const short8*)(sBh + (wn * 64 + t * 16 + fr) * 32 + fq);
      bl[t] = *(const short8*)(sBl + (wn * 64 + t * 16 + fr) * 32 + fq);
    }
#pragma unroll
    for (int mt = 0; mt < 4; ++mt)
#pragma unroll
      for (int nt = 0; nt < 4; ++nt) {
        acc[mt][nt] = __builtin_amdgcn_mfma_f32_16x16x32_bf16(ah[mt], bh[nt], acc[mt][nt], 0, 0, 0);
        acc[mt][nt] = __builtin_amdgcn_mfma_f32_16x16x32_bf16(ah[mt], bl[nt], acc[mt][nt], 0, 0, 0);
        acc[mt][nt] = __builtin_amdgcn_mfma_f32_16x16x32_bf16(al[mt], bh[nt], acc[mt][nt], 0, 0, 0);
      }
    __syncthreads();
  }

  // epilogue: C/D layout col=lane&15, row=(lane>>4)*4+reg  [m89-verified]
  const int ccol = lane & 15, crow4 = (lane >> 4) * 4;
#pragma unroll
  for (int nt = 0; nt < 4; ++nt) {
    const int col = col0 + wn * 64 + nt * 16 + ccol;
    const float bias = be[col];
#pragma unroll
    for (int mt = 0; mt < 4; ++mt) {
      const size_t rb = row0 + wm * 64 + mt * 16 + crow4;
#pragma unroll
      for (int r = 0; r < 4; ++r)
        z[(rb + r) * HID + col] = acc[mt][nt][r] + bias;
    }
  }
}

// ---------------------------------------------------------------------------
// K3: per-row exact-rank threshold + sparsify + decode (fused).
// Register-diet rewrite this round:
//  - only u[32] lives across phases (no uh[], no float copies; values are
//    reconstructed bit-exactly via code2f)
//  - high-16 binary search expressed as 32-bit compares against wave-uniform
//    mid<<16 (no per-element shifts)
//  - all counts via popcll(ballot(...)) -> scalar pipe, no shuffle reduces
//  - cT derived from extraction-loop invariant (count(u>=T) == TOPK - r)
//  - decode gather unrolled x2 for load ILP
// Threshold T and all outputs are bit-identical to the previous version.
// ---------------------------------------------------------------------------
__global__ __launch_bounds__(256, 4) void topk_decode_kernel(
    float* __restrict__ z, const float* __restrict__ WdT,
    const float* __restrict__ bd, float* __restrict__ recon,
    int* __restrict__ flagCount, int* __restrict__ flagList)
{
  __shared__ float2 s_pair[4][64];
  const int w = threadIdx.x >> 6;
  const int lane = threadIdx.x & 63;
  const int row = blockIdx.x * 4 + w;
  float* zr = z + (size_t)row * HID;

  unsigned u[32];
#pragma unroll
  for (int j2 = 0; j2 < 8; ++j2) {
    const float4 t = *(const float4*)(zr + j2 * 256 + lane * 4);
    u[j2 * 4 + 0] = f2code(t.x);
    u[j2 * 4 + 1] = f2code(t.y);
    u[j2 * 4 + 2] = f2code(t.z);
    u[j2 * 4 + 3] = f2code(t.w);
  }

  // ---- lane max + bitonic sort of the 64 lane-maxima ----
  unsigned lmax = u[0];
#pragma unroll
  for (int j = 1; j < 32; ++j) lmax = u[j] > lmax ? u[j] : lmax;

  unsigned sv = lmax;
#pragma unroll
  for (int k = 2; k <= 64; k <<= 1) {
#pragma unroll
    for (int j = k >> 1; j > 0; j >>= 1) {
      const unsigned other = __shfl_xor(sv, j, 64);
      const bool keepSmall = (((lane & j) == 0) == ((lane & k) == 0));
      const bool less = sv < other;
      sv = (keepSmall == less) ? sv : other;
    }
  }
  // ascending by lane: lane 63 = global max, lane 14 = 50th-largest lane-max
  const unsigned L50  = __shfl(sv, 14, 64);
  const unsigned gmax = __shfl(sv, 63, 64);

  // ---- binary search over multiples of 2^16 (== high-16 search) ----
  unsigned blo = L50 >> 16;          // count(u >= blo<<16) >= 50 guaranteed
  unsigned bhi = (gmax >> 16) + 1u;  // count(u >= bhi<<16) == 0
  while (bhi - blo > 1u) {
    const unsigned mid = blo + ((bhi - blo) >> 1);
    const unsigned m32 = mid << 16;
    int c = 0;
#pragma unroll
    for (int j = 0; j < 32; ++j)
      c += (int)__popcll(__ballot(u[j] >= m32));
    if (c >= TOPK) blo = mid; else bhi = mid;
  }
  const unsigned hs = blo << 16;       // bucket start (T's high half == blo)
  const unsigned he = hs + 0x10000u;   // bucket end (finite floats: no wrap)

  int c_he = 0;
#pragma unroll
  for (int j = 0; j < 32; ++j)
    c_he += (int)__popcll(__ballot(u[j] >= he));
  int r = TOPK - c_he;                 // rank of T inside bucket, >= 1

  // ---- extract r-th largest (with multiplicity) inside [hs, he) ----
  unsigned cur = he;
  while (r > 0) {
    unsigned cand = 0u;
#pragma unroll
    for (int j = 0; j < 32; ++j) {
      const unsigned x = (u[j] >= hs && u[j] < cur) ? u[j] : 0u;
      cand = x > cand ? x : cand;
    }
    cand = wave_max_u(cand);
    int e = 0;
#pragma unroll
    for (int j = 0; j < 32; ++j)
      e += (int)__popcll(__ballot(u[j] == cand));
    r -= e;
    cur = cand;
  }
  const unsigned T = cur;
  const int cT = TOPK - r;             // invariant: count(u >= T) == TOPK - r

  // ---- 51st value (max below T) for the near-tie flag ----
  unsigned below = 0u;
#pragma unroll
  for (int j = 0; j < 32; ++j) {
    const unsigned x = (u[j] < T) ? u[j] : 0u;
    below = x > below ? x : below;
  }
  below = wave_max_u(below);
  if (lane == 0) {
    const float gap = (cT > TOPK) ? 0.0f : (code2f(T) - code2f(below));
    if (gap < MARGIN) {
      const int idx = atomicAdd(flagCount, 1);
      flagList[idx] = row;
    }
  }

  // ---- sparsify in place (code2f(f2code(v)) == v bitwise) ----
#pragma unroll
  for (int j2 = 0; j2 < 8; ++j2) {
    float4 o;
    o.x = (u[j2 * 4 + 0] >= T) ? code2f(u[j2 * 4 + 0]) : 0.0f;
    o.y = (u[j2 * 4 + 1] >= T) ? code2f(u[j2 * 4 + 1]) : 0.0f;
    o.z = (u[j2 * 4 + 2] >= T) ? code2f(u[j2 * 4 + 2]) : 0.0f;
    o.w = (u[j2 * 4 + 3] >= T) ? code2f(u[j2 * 4 + 3]) : 0.0f;
    *(float4*)(zr + j2 * 256 + lane * 4) = o;
  }

  // ---- ballot-compact survivors ----
  s_pair[w][lane] = make_float2(0.0f, __int_as_float(0));
  int base = 0;
#pragma unroll
  for (int j = 0; j < 32; ++j) {
    const bool pass = (u[j] >= T);
    const unsigned long long mask = __ballot(pass);
    if (pass) {
      const int pos = base + __popcll(mask & ((1ull << lane) - 1ull));
      if (pos < 64) {
        const int hidx = (j >> 2) * 256 + lane * 4 + (j & 3);
        s_pair[w][pos] = make_float2(code2f(u[j]), __int_as_float(hidx));
      }
    }
    base += __popcll(mask);
  }
  const int cnt = (base < 64) ? base : 64;

  // ---- decode: acc = b_dec + sum z_i * WdT[h_i], gathers unrolled x2 ----
  float acc[8];
  {
    const float4 b0 = *(const float4*)(bd + lane * 8);
    const float4 b1 = *(const float4*)(bd + lane * 8 + 4);
    acc[0] = b0.x; acc[1] = b0.y; acc[2] = b0.z; acc[3] = b0.w;
    acc[4] = b1.x; acc[5] = b1.y; acc[6] = b1.z; acc[7] = b1.w;
  }
  int i = 0;
  for (; i + 2 <= cnt; i += 2) {
    const float2 p0 = s_pair[w][i];
    const float2 p1 = s_pair[w][i + 1];
    const float* wr0 = WdT + (size_t)__float_as_int(p0.y) * IN_DIM + lane * 8;
    const float* wr1 = WdT + (size_t)__float_as_int(p1.y) * IN_DIM + lane * 8;
    const float4 a0 = *(const float4*)wr0;
    const float4 a1 = *(const float4*)(wr0 + 4);
    const float4 b0 = *(const float4*)wr1;
    const float4 b1 = *(const float4*)(wr1 + 4);
    acc[0] += p0.x * a0.x; acc[1] += p0.x * a0.y;
    acc[2] += p0.x * a0.z; acc[3] += p0.x * a0.w;
    acc[4] += p0.x * a1.x; acc[5] += p0.x * a1.y;
    acc[6] += p0.x * a1.z; acc[7] += p0.x * a1.w;
    acc[0] += p1.x * b0.x; acc[1] += p1.x * b0.y;
    acc[2] += p1.x * b0.z; acc[3] += p1.x * b0.w;
    acc[4] += p1.x * b1.x; acc[5] += p1.x * b1.y;
    acc[6] += p1.x * b1.z; acc[7] += p1.x * b1.w;
  }
  if (i < cnt) {
    const float2 p0 = s_pair[w][i];
    const float* wr0 = WdT + (size_t)__float_as_int(p0.y) * IN_DIM + lane * 8;
    const float4 a0 = *(const float4*)wr0;
    const float4 a1 = *(const float4*)(wr0 + 4);
    acc[0] += p0.x * a0.x; acc[1] += p0.x * a0.y;
    acc[2] += p0.x * a0.z; acc[3] += p0.x * a0.w;
    acc[4] += p0.x * a1.x; acc[5] += p0.x * a1.y;
    acc[6] += p0.x * a1.z; acc[7] += p0.x * a1.w;
  }

  float* rr = recon + (size_t)row * IN_DIM + lane * 8;
  *(float4*)(rr)     = make_float4(acc[0], acc[1], acc[2], acc[3]);
  *(float4*)(rr + 4) = make_float4(acc[4], acc[5], acc[6], acc[7]);
}

// ---------------------------------------------------------------------------
// K4: exact fixup for flagged rows — recompute z with sequential ascending
// fp32 FMA (the R1 semantics that matched the np reference), redo selection,
// rewrite z_sparse row and recon row. One wave (64-thread block) per row.
// NOTE: summation order is load-bearing (bit-match vs reference) — do not
// reorder the FMA chain.
// ---------------------------------------------------------------------------
__global__ __launch_bounds__(64) void fixup_kernel(
    const float* __restrict__ x, const float* __restrict__ We,
    const float* __restrict__ be, const float* __restrict__ bd,
    const float* __restrict__ pb, const float* __restrict__ WdT,
    const int* __restrict__ flagCount, const int* __restrict__ flagList,
    float* __restrict__ z, float* __restrict__ recon)
{
  __shared__ float sxc[IN_DIM];
  __shared__ float2 spair[64];
  const int lane = threadIdx.x;
  const int nflag = *flagCount;

  for (int fi = blockIdx.x; fi < nflag; fi += gridDim.x) {
    const int row = flagList[fi];
#pragma unroll
    for (int t = 0; t < 8; ++t) {
      const int k = lane + t * 64;
      sxc[k] = x[(size_t)row * IN_DIM + k] - (bd[k] + pb[k]);
    }
    __syncthreads();

    float v[32];
    unsigned u[32];
#pragma unroll
    for (int j = 0; j < 32; ++j) {
      const int f = lane + 64 * j;
      const float* wr = We + (size_t)f * IN_DIM;
      float a = 0.f;
      for (int k4 = 0; k4 < IN_DIM; k4 += 4) {
        const float4 w4 = *(const float4*)(wr + k4);
        a = fmaf(sxc[k4 + 0], w4.x, a);
        a = fmaf(sxc[k4 + 1], w4.y, a);
        a = fmaf(sxc[k4 + 2], w4.z, a);
        a = fmaf(sxc[k4 + 3], w4.w, a);
      }
      v[j] = a + be[f];
      u[j] = f2code(v[j]);
    }

    unsigned lo = 0u, hi = 0xFFFFFFFFu;
    while (hi - lo > 1u) {
      const unsigned mid = lo + ((hi - lo) >> 1);
      int c = 0;
#pragma unroll
      for (int j = 0; j < 32; ++j) c += (u[j] >= mid) ? 1 : 0;
#pragma unroll
      for (int s = 32; s > 0; s >>= 1) c += __shfl_xor(c, s, 64);
      if (c >= TOPK) lo = mid; else hi = mid;
    }

    // rewrite z_sparse row
#pragma unroll
    for (int j = 0; j < 32; ++j)
      z[(size_t)row * HID + lane + 64 * j] = (u[j] >= lo) ? v[j] : 0.0f;

    // compact + recon
    spair[lane] = make_float2(0.0f, __int_as_float(0));
    __syncthreads();
    int base = 0;
#pragma unroll
    for (int j = 0; j < 32; ++j) {
      const bool pass = (u[j] >= lo);
      const unsigned long long mask = __ballot(pass);
      if (pass) {
        const int pos = base + __popcll(mask & ((1ull << lane) - 1ull));
        if (pos < 64) spair[pos] = make_float2(v[j], __int_as_float(lane + 64 * j));
      }
      base += __popcll(mask);
    }
    __syncthreads();
    const int cnt = (base < 64) ? base : 64;

    float acc[8];
    {
      const float4 b0 = *(const float4*)(bd + lane * 8);
      const float4 b1 = *(const float4*)(bd + lane * 8 + 4);
      acc[0] = b0.x; acc[1] = b0.y; acc[2] = b0.z; acc[3] = b0.w;
      acc[4] = b1.x; acc[5] = b1.y; acc[6] = b1.z; acc[7] = b1.w;
    }
    for (int i = 0; i < cnt; ++i) {
      const float2 p = spair[i];
      const float* wr = WdT + (size_t)__float_as_int(p.y) * IN_DIM + lane * 8;
      const float4 w0 = *(const float4*)wr;
      const float4 w1 = *(const float4*)(wr + 4);
      acc[0] += p.x * w0.x; acc[1] += p.x * w0.y;
      acc[2] += p.x * w0.z; acc[3] += p.x * w0.w;
      acc[4] += p.x * w1.x; acc[5] += p.x * w1.y;
      acc[6] += p.x * w1.z; acc[7] += p.x * w1.w;
    }
    float* rr = recon + (size_t)row * IN_DIM + lane * 8;
    *(float4*)(rr) = make_float4(acc[0], acc[1], acc[2], acc[3]);
    *(float4*)(rr + 4) = make_float4(acc[4], acc[5], acc[6], acc[7]);
    __syncthreads();
  }
}

// ---------------------------------------------------------------------------
extern "C" void kernel_launch(void* const* d_in, const int* in_sizes, int n_in,
                              void* d_out, int out_size, void* d_ws, size_t ws_size,
                              hipStream_t stream)
{
  const float* x  = (const float*)d_in[0];
  const float* We = (const float*)d_in[1];
  const float* be = (const float*)d_in[2];
  const float* Wd = (const float*)d_in[3];
  const float* bd = (const float*)d_in[4];
  const float* pb = (const float*)d_in[5];

  const int M = in_sizes[0] / IN_DIM;   // 65536

  float* recon = (float*)d_out;                        // M x 512
  float* zs    = (float*)d_out + (size_t)M * IN_DIM;   // M x 2048 (z -> z_sparse)
  // xcHi/xcLo live in the recon region (dead until topk_decode writes it)
  unsigned short* xcHi = (unsigned short*)recon;                    // M*512 u16
  unsigned short* xcLo = xcHi + (size_t)M * IN_DIM;                 // M*512 u16

  char* ws = (char*)d_ws;
  float* WdT           = (float*)ws;                    // 4 MB
  unsigned short* WeHi = (unsigned short*)(ws + (4 << 20));   // 2 MB
  unsigned short* WeLo = (unsigned short*)(ws + (6 << 20));   // 2 MB
  int* flagCount       = (int*)(ws + (8 << 20));
  int* flagList        = flagCount + 16;

  hipMemsetAsync(flagCount, 0, 64, stream);
  transpose_wdec_kernel<<<1024, 256, 0, stream>>>(Wd, WdT);
  split_we_kernel<<<(HID * IN_DIM / 4) / 256, 256, 0, stream>>>(We, WeHi, WeLo);
  split_x_kernel<<<(M * (IN_DIM / 4)) / 256, 256, 0, stream>>>(x, bd, pb, xcHi, xcLo);
  enc_gemm_mfma_kernel<<<(M / 128) * (HID / 128), 256, 0, stream>>>(
      xcHi, xcLo, WeHi, WeLo, be, zs);
  topk_decode_kernel<<<M / 4, 256, 0, stream>>>(zs, WdT, bd, recon, flagCount, flagList);
  fixup_kernel<<<2048, 64, 0, stream>>>(x, We, be, bd, pb, WdT,
                                        flagCount, flagList, zs, recon);
}

// Round 3
// 2019.050 us; speedup vs baseline: 1.1157x; 1.0153x over previous
//
#include <hip/hip_runtime.h>
#include <cstdint>
#include <cstddef>

#define IN_DIM 512
#define HID 2048
#define TOPK 50
#define MARGIN 4e-5f

typedef __attribute__((ext_vector_type(8))) short short8;
typedef __attribute__((ext_vector_type(4))) float f32x4;

__device__ __forceinline__ unsigned short f2bf(float f) {
  unsigned b = __float_as_uint(f);
  b += 0x7fffu + ((b >> 16) & 1u);          // round-to-nearest-even
  return (unsigned short)(b >> 16);
}
__device__ __forceinline__ float bf2f(unsigned short u) {
  return __uint_as_float(((unsigned)u) << 16);
}
__device__ __forceinline__ unsigned f2code(float f) {
  const unsigned b = __float_as_uint(f);
  return (b & 0x80000000u) ? ~b : (b | 0x80000000u);   // order-preserving
}
__device__ __forceinline__ float code2f(unsigned t) {
  return __uint_as_float((t & 0x80000000u) ? (t & 0x7fffffffu) : ~t);
}
__device__ __forceinline__ void dma16(const void* g, void* l) {
  __builtin_amdgcn_global_load_lds(
      (const __attribute__((address_space(1))) void*)g,
      (__attribute__((address_space(3))) void*)l, 16, 0, 0);
}
__device__ __forceinline__ unsigned wave_max_u(unsigned m) {
#pragma unroll
  for (int s = 32; s > 0; s >>= 1) {
    const unsigned o = __shfl_xor(m, s, 64);
    m = o > m ? o : m;
  }
  return m;
}

// ---------------------------------------------------------------------------
// K0: transpose W_dec (512 x 2048) -> W_dec_T (2048 x 512)
// ---------------------------------------------------------------------------
__global__ __launch_bounds__(256) void transpose_wdec_kernel(
    const float* __restrict__ Wd, float* __restrict__ WdT)
{
  __shared__ float tile[32][33];
  const int bx = blockIdx.x & 63;
  const int by = blockIdx.x >> 6;
  const int tx = threadIdx.x & 31;
  const int ty = threadIdx.x >> 5;
#pragma unroll
  for (int i = 0; i < 4; ++i)
    tile[ty + i * 8][tx] = Wd[(size_t)(by * 32 + ty + i * 8) * HID + bx * 32 + tx];
  __syncthreads();
#pragma unroll
  for (int i = 0; i < 4; ++i)
    WdT[(size_t)(bx * 32 + ty + i * 8) * IN_DIM + by * 32 + tx] = tile[tx][ty + i * 8];
}

// ---------------------------------------------------------------------------
// K1a: split W_enc (2048x512 fp32) -> WeHi, WeLo (bf16 as ushort)
// ---------------------------------------------------------------------------
__global__ __launch_bounds__(256) void split_we_kernel(
    const float* __restrict__ We, unsigned short* __restrict__ wh,
    unsigned short* __restrict__ wl)
{
  const int i4 = blockIdx.x * 256 + threadIdx.x;   // HID*IN_DIM/4 total
  const float4 v = ((const float4*)We)[i4];
  ushort4 h, l;
  h.x = f2bf(v.x); l.x = f2bf(v.x - bf2f(h.x));
  h.y = f2bf(v.y); l.y = f2bf(v.y - bf2f(h.y));
  h.z = f2bf(v.z); l.z = f2bf(v.z - bf2f(h.z));
  h.w = f2bf(v.w); l.w = f2bf(v.w - bf2f(h.w));
  ((ushort4*)wh)[i4] = h;
  ((ushort4*)wl)[i4] = l;
}

// ---------------------------------------------------------------------------
// K1b: xc = x - (b_dec + pre_bias); split -> xcHi, xcLo (stored in recon area)
// ---------------------------------------------------------------------------
__global__ __launch_bounds__(256) void split_x_kernel(
    const float* __restrict__ x, const float* __restrict__ bd,
    const float* __restrict__ pb, unsigned short* __restrict__ xh,
    unsigned short* __restrict__ xl)
{
  const int i4 = blockIdx.x * 256 + threadIdx.x;   // M*IN_DIM/4 total
  const int k4 = (i4 & 127) * 4;
  const float4 v = ((const float4*)x)[i4];
  const float4 b = *(const float4*)(bd + k4);
  const float4 p = *(const float4*)(pb + k4);
  float c0 = v.x - (b.x + p.x);
  float c1 = v.y - (b.y + p.y);
  float c2 = v.z - (b.z + p.z);
  float c3 = v.w - (b.w + p.w);
  ushort4 h, l;
  h.x = f2bf(c0); l.x = f2bf(c0 - bf2f(h.x));
  h.y = f2bf(c1); l.y = f2bf(c1 - bf2f(h.y));
  h.z = f2bf(c2); l.z = f2bf(c2 - bf2f(h.z));
  h.w = f2bf(c3); l.w = f2bf(c3 - bf2f(h.w));
  ((ushort4*)xh)[i4] = h;
  ((ushort4*)xl)[i4] = l;
}

// ---------------------------------------------------------------------------
// K2 (this round): z = xc @ We^T + be as a SINGLE bf16 GEMM with K'=1536:
//   z = [xh | xh | xl] . [wh | wl | wh]^T   (24 K-tiles of 64; tile tt:
//   A = tt<16 ? xh : xl, B = (tt>>3)==1 ? wl : wh, col = 64*(tt&7))
// 256x256 tile, 8 waves (2Mx4N), BK=64 as two K-halves of 32, 8-phase
// schedule with counted vmcnt(8) (4 half-tiles in flight, never drained),
// chunk-XOR swizzle q^=(row>>1)&3 on both stage-source and ds_read
// (involution => correctness-independent), setprio around MFMA clusters.
// LDS 128 KB, 1 block/CU.
//
// Stage schedule per iteration I (tiles t=2I, t+1):
//   ph1: A.k1(t+1)->sA[1][1]  ph2: B.k1(t+1)->sB[1][1]  [vmcnt(8)]
//   ph3: A.k0(t+2)->sA[0][0]  ph4: B.k0(t+2)->sB[0][0]  [vmcnt(8)]
//   ph5: A.k1(t+2)->sA[0][1]  ph6: B.k1(t+2)->sB[0][1]  [vmcnt(8)]
//   ph7: A.k0(t+3)->sA[1][0]  ph8: B.k0(t+3)->sB[1][0]  [vmcnt(8)]
// Every buffer is staged only after the phase-ending barrier of its last
// reader; every half is staged >=5 phases before first read; vmcnt(8) at
// even-phase ends == "everything issued >=4 phases ago has landed".
// Tail iterations wrap stage tiles to 0/1 (data unused) so the vmcnt
// counting stays valid — do not "optimize" them away.
// ---------------------------------------------------------------------------
__device__ __forceinline__ short8 ldfrag(const unsigned short* h, int row, int fq3) {
  const int qs = fq3 ^ ((row >> 1) & 3);
  return *(const short8*)(h + row * 32 + qs * 8);
}

#define STAGE_A(PP, KH, TT) do {                                   \
  const unsigned short* g_ = ((TT) & 16) ? xl : xh;                \
  const int kc_ = (((TT) & 7) << 6) + (KH) * 32;                   \
  dma16(g_ + aoff0 + kc_, &sA[PP][KH][wv * 512]);                  \
  dma16(g_ + aoff1 + kc_, &sA[PP][KH][wv * 512 + 4096]);           \
} while (0)

#define STAGE_B(PP, KH, TT) do {                                   \
  const unsigned short* g_ = ((((TT) >> 3) & 3) == 1) ? wl : wh;   \
  const int kc_ = (((TT) & 7) << 6) + (KH) * 32;                   \
  dma16(g_ + boff0 + kc_, &sB[PP][KH][wv * 512]);                  \
  dma16(g_ + boff1 + kc_, &sB[PP][KH][wv * 512 + 4096]);           \
} while (0)

#define MFMA_ROW(MH, MT, AV)                                                              \
  acc[(MH)*4+(MT)][0] = __builtin_amdgcn_mfma_f32_16x16x32_bf16(AV, b0, acc[(MH)*4+(MT)][0], 0, 0, 0); \
  acc[(MH)*4+(MT)][1] = __builtin_amdgcn_mfma_f32_16x16x32_bf16(AV, b1, acc[(MH)*4+(MT)][1], 0, 0, 0); \
  acc[(MH)*4+(MT)][2] = __builtin_amdgcn_mfma_f32_16x16x32_bf16(AV, b2, acc[(MH)*4+(MT)][2], 0, 0, 0); \
  acc[(MH)*4+(MT)][3] = __builtin_amdgcn_mfma_f32_16x16x32_bf16(AV, b3, acc[(MH)*4+(MT)][3], 0, 0, 0);

#define PHASE(PP, KH, MH, LOADB, STAGE_STMT, DO_VM) do {           \
  const unsigned short* hA_ = &sA[PP][KH][0];                      \
  const int ar_ = wm * 128 + (MH) * 64 + fr;                       \
  a0 = ldfrag(hA_, ar_ +  0, fq3);                                 \
  a1 = ldfrag(hA_, ar_ + 16, fq3);                                 \
  a2 = ldfrag(hA_, ar_ + 32, fq3);                                 \
  a3 = ldfrag(hA_, ar_ + 48, fq3);                                 \
  if (LOADB) {                                                     \
    const unsigned short* hB_ = &sB[PP][KH][0];                    \
    const int br_ = wn * 64 + fr;                                  \
    b0 = ldfrag(hB_, br_ +  0, fq3);                               \
    b1 = ldfrag(hB_, br_ + 16, fq3);                               \
    b2 = ldfrag(hB_, br_ + 32, fq3);                               \
    b3 = ldfrag(hB_, br_ + 48, fq3);                               \
  }                                                                \
  STAGE_STMT;                                                      \
  __builtin_amdgcn_sched_barrier(0);                               \
  __builtin_amdgcn_s_barrier();                                    \
  __builtin_amdgcn_sched_barrier(0);                               \
  __builtin_amdgcn_s_setprio(1);                                   \
  MFMA_ROW(MH, 0, a0)                                              \
  MFMA_ROW(MH, 1, a1)                                              \
  MFMA_ROW(MH, 2, a2)                                              \
  MFMA_ROW(MH, 3, a3)                                              \
  __builtin_amdgcn_s_setprio(0);                                   \
  __builtin_amdgcn_sched_barrier(0);                               \
  if (DO_VM) asm volatile("s_waitcnt vmcnt(8)" ::: "memory");      \
  __builtin_amdgcn_s_barrier();                                    \
  __builtin_amdgcn_sched_barrier(0);                               \
} while (0)

__global__ __launch_bounds__(512, 2) void enc_gemm_8ph_kernel(
    const unsigned short* __restrict__ xh, const unsigned short* __restrict__ xl,
    const unsigned short* __restrict__ wh, const unsigned short* __restrict__ wl,
    const float* __restrict__ be, float* __restrict__ z)
{
  __shared__ __align__(16) unsigned short sA[2][2][256 * 32];   // 64 KB
  __shared__ __align__(16) unsigned short sB[2][2][256 * 32];   // 64 KB

  const int tid = threadIdx.x;
  const int lane = tid & 63, wv = tid >> 6;
  const int wm = wv >> 2, wn = wv & 3;          // 2 x 4 wave grid
  const int fr = lane & 15, fq3 = lane >> 4;

  // bijective XCD-chunk swizzle (nwg = 2048, %8 == 0)
  const int bid = blockIdx.x;
  const int sb = (bid & 7) * 256 + (bid >> 3);
  const size_t row0 = (size_t)(sb >> 3) * 256;
  const int col0 = (sb & 7) * 256;

  f32x4 acc[8][4];
#pragma unroll
  for (int i = 0; i < 8; ++i)
#pragma unroll
    for (int j = 0; j < 4; ++j) acc[i][j] = (f32x4){0.f, 0.f, 0.f, 0.f};

  // per-lane invariant stage-source offsets (chunk c: r=c>>2, q=c&3,
  // swizzled q' = q ^ ((r>>1)&3)); chunk set 0: c=tid, set 1: c=tid+512
  const int r0c = tid >> 2, q0c = tid & 3;
  const int qs0 = q0c ^ ((r0c >> 1) & 3);
  const int c1c = tid + 512;
  const int r1c = c1c >> 2, q1c = c1c & 3;
  const int qs1 = q1c ^ ((r1c >> 1) & 3);
  const size_t aoff0 = (row0 + (size_t)r0c) * IN_DIM + qs0 * 8;
  const size_t aoff1 = (row0 + (size_t)r1c) * IN_DIM + qs1 * 8;
  const size_t boff0 = ((size_t)col0 + r0c) * IN_DIM + qs0 * 8;
  const size_t boff1 = ((size_t)col0 + r1c) * IN_DIM + qs1 * 8;

  // prologue: stage A.k0(0), B.k0(0), A.k1(0), B.k1(0), A.k0(1), B.k0(1)
  STAGE_A(0, 0, 0); STAGE_B(0, 0, 0);
  STAGE_A(0, 1, 0); STAGE_B(0, 1, 0);
  STAGE_A(1, 0, 1); STAGE_B(1, 0, 1);
  asm volatile("s_waitcnt vmcnt(8)" ::: "memory");   // oldest 4 loads (=A/B.k0(0)) done
  __builtin_amdgcn_s_barrier();
  __builtin_amdgcn_sched_barrier(0);

  short8 a0, a1, a2, a3, b0, b1, b2, b3;
  for (int I = 0; I < 12; ++I) {
    const int t1 = 2 * I + 1;
    int t2 = 2 * I + 2; if (t2 >= 24) t2 -= 24;   // tail wraps keep vmcnt valid
    int t3 = 2 * I + 3; if (t3 >= 24) t3 -= 24;
    PHASE(0, 0, 0, true , STAGE_A(1, 1, t1), false);
    PHASE(0, 0, 1, false, STAGE_B(1, 1, t1), true );
    PHASE(0, 1, 0, true , STAGE_A(0, 0, t2), false);
    PHASE(0, 1, 1, false, STAGE_B(0, 0, t2), true );
    PHASE(1, 0, 0, true , STAGE_A(0, 1, t2), false);
    PHASE(1, 0, 1, false, STAGE_B(0, 1, t2), true );
    PHASE(1, 1, 0, true , STAGE_A(1, 0, t3), false);
    PHASE(1, 1, 1, false, STAGE_B(1, 0, t3), true );
  }

  // epilogue: C/D layout col=lane&15, row=(lane>>4)*4+reg  [m89-verified]
  const int ccol = lane & 15, crow4 = (lane >> 4) * 4;
#pragma unroll
  for (int nt = 0; nt < 4; ++nt) {
    const int col = col0 + wn * 64 + nt * 16 + ccol;
    const float bias = be[col];
#pragma unroll
    for (int mt8 = 0; mt8 < 8; ++mt8) {
      const size_t rb = row0 + wm * 128 + mt8 * 16 + crow4;
#pragma unroll
      for (int r = 0; r < 4; ++r)
        z[(rb + r) * HID + col] = acc[mt8][nt][r] + bias;
    }
  }
}

// ---------------------------------------------------------------------------
// K3: per-row exact-rank threshold + sparsify + decode (fused). Unchanged
// from round 2 (register-diet selection; bit-identical threshold semantics).
// ---------------------------------------------------------------------------
__global__ __launch_bounds__(256, 4) void topk_decode_kernel(
    float* __restrict__ z, const float* __restrict__ WdT,
    const float* __restrict__ bd, float* __restrict__ recon,
    int* __restrict__ flagCount, int* __restrict__ flagList)
{
  __shared__ float2 s_pair[4][64];
  const int w = threadIdx.x >> 6;
  const int lane = threadIdx.x & 63;
  const int row = blockIdx.x * 4 + w;
  float* zr = z + (size_t)row * HID;

  unsigned u[32];
#pragma unroll
  for (int j2 = 0; j2 < 8; ++j2) {
    const float4 t = *(const float4*)(zr + j2 * 256 + lane * 4);
    u[j2 * 4 + 0] = f2code(t.x);
    u[j2 * 4 + 1] = f2code(t.y);
    u[j2 * 4 + 2] = f2code(t.z);
    u[j2 * 4 + 3] = f2code(t.w);
  }

  // ---- lane max + bitonic sort of the 64 lane-maxima ----
  unsigned lmax = u[0];
#pragma unroll
  for (int j = 1; j < 32; ++j) lmax = u[j] > lmax ? u[j] : lmax;

  unsigned sv = lmax;
#pragma unroll
  for (int k = 2; k <= 64; k <<= 1) {
#pragma unroll
    for (int j = k >> 1; j > 0; j >>= 1) {
      const unsigned other = __shfl_xor(sv, j, 64);
      const bool keepSmall = (((lane & j) == 0) == ((lane & k) == 0));
      const bool less = sv < other;
      sv = (keepSmall == less) ? sv : other;
    }
  }
  // ascending by lane: lane 63 = global max, lane 14 = 50th-largest lane-max
  const unsigned L50  = __shfl(sv, 14, 64);
  const unsigned gmax = __shfl(sv, 63, 64);

  // ---- binary search over multiples of 2^16 (== high-16 search) ----
  unsigned blo = L50 >> 16;          // count(u >= blo<<16) >= 50 guaranteed
  unsigned bhi = (gmax >> 16) + 1u;  // count(u >= bhi<<16) == 0
  while (bhi - blo > 1u) {
    const unsigned mid = blo + ((bhi - blo) >> 1);
    const unsigned m32 = mid << 16;
    int c = 0;
#pragma unroll
    for (int j = 0; j < 32; ++j)
      c += (int)__popcll(__ballot(u[j] >= m32));
    if (c >= TOPK) blo = mid; else bhi = mid;
  }
  const unsigned hs = blo << 16;       // bucket start (T's high half == blo)
  const unsigned he = hs + 0x10000u;   // bucket end (finite floats: no wrap)

  int c_he = 0;
#pragma unroll
  for (int j = 0; j < 32; ++j)
    c_he += (int)__popcll(__ballot(u[j] >= he));
  int r = TOPK - c_he;                 // rank of T inside bucket, >= 1

  // ---- extract r-th largest (with multiplicity) inside [hs, he) ----
  unsigned cur = he;
  while (r > 0) {
    unsigned cand = 0u;
#pragma unroll
    for (int j = 0; j < 32; ++j) {
      const unsigned x = (u[j] >= hs && u[j] < cur) ? u[j] : 0u;
      cand = x > cand ? x : cand;
    }
    cand = wave_max_u(cand);
    int e = 0;
#pragma unroll
    for (int j = 0; j < 32; ++j)
      e += (int)__popcll(__ballot(u[j] == cand));
    r -= e;
    cur = cand;
  }
  const unsigned T = cur;
  const int cT = TOPK - r;             // invariant: count(u >= T) == TOPK - r

  // ---- 51st value (max below T) for the near-tie flag ----
  unsigned below = 0u;
#pragma unroll
  for (int j = 0; j < 32; ++j) {
    const unsigned x = (u[j] < T) ? u[j] : 0u;
    below = x > below ? x : below;
  }
  below = wave_max_u(below);
  if (lane == 0) {
    const float gap = (cT > TOPK) ? 0.0f : (code2f(T) - code2f(below));
    if (gap < MARGIN) {
      const int idx = atomicAdd(flagCount, 1);
      flagList[idx] = row;
    }
  }

  // ---- sparsify in place (code2f(f2code(v)) == v bitwise) ----
#pragma unroll
  for (int j2 = 0; j2 < 8; ++j2) {
    float4 o;
    o.x = (u[j2 * 4 + 0] >= T) ? code2f(u[j2 * 4 + 0]) : 0.0f;
    o.y = (u[j2 * 4 + 1] >= T) ? code2f(u[j2 * 4 + 1]) : 0.0f;
    o.z = (u[j2 * 4 + 2] >= T) ? code2f(u[j2 * 4 + 2]) : 0.0f;
    o.w = (u[j2 * 4 + 3] >= T) ? code2f(u[j2 * 4 + 3]) : 0.0f;
    *(float4*)(zr + j2 * 256 + lane * 4) = o;
  }

  // ---- ballot-compact survivors ----
  s_pair[w][lane] = make_float2(0.0f, __int_as_float(0));
  int base = 0;
#pragma unroll
  for (int j = 0; j < 32; ++j) {
    const bool pass = (u[j] >= T);
    const unsigned long long mask = __ballot(pass);
    if (pass) {
      const int pos = base + __popcll(mask & ((1ull << lane) - 1ull));
      if (pos < 64) {
        const int hidx = (j >> 2) * 256 + lane * 4 + (j & 3);
        s_pair[w][pos] = make_float2(code2f(u[j]), __int_as_float(hidx));
      }
    }
    base += __popcll(mask);
  }
  const int cnt = (base < 64) ? base : 64;

  // ---- decode: acc = b_dec + sum z_i * WdT[h_i], gathers unrolled x2 ----
  float acc[8];
  {
    const float4 b0 = *(const float4*)(bd + lane * 8);
    const float4 b1 = *(const float4*)(bd + lane * 8 + 4);
    acc[0] = b0.x; acc[1] = b0.y; acc[2] = b0.z; acc[3] = b0.w;
    acc[4] = b1.x; acc[5] = b1.y; acc[6] = b1.z; acc[7] = b1.w;
  }
  int i = 0;
  for (; i + 2 <= cnt; i += 2) {
    const float2 p0 = s_pair[w][i];
    const float2 p1 = s_pair[w][i + 1];
    const float* wr0 = WdT + (size_t)__float_as_int(p0.y) * IN_DIM + lane * 8;
    const float* wr1 = WdT + (size_t)__float_as_int(p1.y) * IN_DIM + lane * 8;
    const float4 a0 = *(const float4*)wr0;
    const float4 a1 = *(const float4*)(wr0 + 4);
    const float4 b0 = *(const float4*)wr1;
    const float4 b1 = *(const float4*)(wr1 + 4);
    acc[0] += p0.x * a0.x; acc[1] += p0.x * a0.y;
    acc[2] += p0.x * a0.z; acc[3] += p0.x * a0.w;
    acc[4] += p0.x * a1.x; acc[5] += p0.x * a1.y;
    acc[6] += p0.x * a1.z; acc[7] += p0.x * a1.w;
    acc[0] += p1.x * b0.x; acc[1] += p1.x * b0.y;
    acc[2] += p1.x * b0.z; acc[3] += p1.x * b0.w;
    acc[4] += p1.x * b1.x; acc[5] += p1.x * b1.y;
    acc[6] += p1.x * b1.z; acc[7] += p1.x * b1.w;
  }
  if (i < cnt) {
    const float2 p0 = s_pair[w][i];
    const float* wr0 = WdT + (size_t)__float_as_int(p0.y) * IN_DIM + lane * 8;
    const float4 a0 = *(const float4*)wr0;
    const float4 a1 = *(const float4*)(wr0 + 4);
    acc[0] += p0.x * a0.x; acc[1] += p0.x * a0.y;
    acc[2] += p0.x * a0.z; acc[3] += p0.x * a0.w;
    acc[4] += p0.x * a1.x; acc[5] += p0.x * a1.y;
    acc[6] += p0.x * a1.z; acc[7] += p0.x * a1.w;
  }

  float* rr = recon + (size_t)row * IN_DIM + lane * 8;
  *(float4*)(rr)     = make_float4(acc[0], acc[1], acc[2], acc[3]);
  *(float4*)(rr + 4) = make_float4(acc[4], acc[5], acc[6], acc[7]);
}

// ---------------------------------------------------------------------------
// K4: exact fixup for flagged rows — recompute z with sequential ascending
// fp32 FMA, redo selection, rewrite z_sparse row and recon row. One wave
// per row. Summation order is load-bearing — do not reorder the FMA chain.
// ---------------------------------------------------------------------------
__global__ __launch_bounds__(64) void fixup_kernel(
    const float* __restrict__ x, const float* __restrict__ We,
    const float* __restrict__ be, const float* __restrict__ bd,
    const float* __restrict__ pb, const float* __restrict__ WdT,
    const int* __restrict__ flagCount, const int* __restrict__ flagList,
    float* __restrict__ z, float* __restrict__ recon)
{
  __shared__ float sxc[IN_DIM];
  __shared__ float2 spair[64];
  const int lane = threadIdx.x;
  const int nflag = *flagCount;

  for (int fi = blockIdx.x; fi < nflag; fi += gridDim.x) {
    const int row = flagList[fi];
#pragma unroll
    for (int t = 0; t < 8; ++t) {
      const int k = lane + t * 64;
      sxc[k] = x[(size_t)row * IN_DIM + k] - (bd[k] + pb[k]);
    }
    __syncthreads();

    float v[32];
    unsigned u[32];
#pragma unroll
    for (int j = 0; j < 32; ++j) {
      const int f = lane + 64 * j;
      const float* wr = We + (size_t)f * IN_DIM;
      float a = 0.f;
      for (int k4 = 0; k4 < IN_DIM; k4 += 4) {
        const float4 w4 = *(const float4*)(wr + k4);
        a = fmaf(sxc[k4 + 0], w4.x, a);
        a = fmaf(sxc[k4 + 1], w4.y, a);
        a = fmaf(sxc[k4 + 2], w4.z, a);
        a = fmaf(sxc[k4 + 3], w4.w, a);
      }
      v[j] = a + be[f];
      u[j] = f2code(v[j]);
    }

    unsigned lo = 0u, hi = 0xFFFFFFFFu;
    while (hi - lo > 1u) {
      const unsigned mid = lo + ((hi - lo) >> 1);
      int c = 0;
#pragma unroll
      for (int j = 0; j < 32; ++j) c += (u[j] >= mid) ? 1 : 0;
#pragma unroll
      for (int s = 32; s > 0; s >>= 1) c += __shfl_xor(c, s, 64);
      if (c >= TOPK) lo = mid; else hi = mid;
    }

    // rewrite z_sparse row
#pragma unroll
    for (int j = 0; j < 32; ++j)
      z[(size_t)row * HID + lane + 64 * j] = (u[j] >= lo) ? v[j] : 0.0f;

    // compact + recon
    spair[lane] = make_float2(0.0f, __int_as_float(0));
    __syncthreads();
    int base = 0;
#pragma unroll
    for (int j = 0; j < 32; ++j) {
      const bool pass = (u[j] >= lo);
      const unsigned long long mask = __ballot(pass);
      if (pass) {
        const int pos = base + __popcll(mask & ((1ull << lane) - 1ull));
        if (pos < 64) spair[pos] = make_float2(v[j], __int_as_float(lane + 64 * j));
      }
      base += __popcll(mask);
    }
    __syncthreads();
    const int cnt = (base < 64) ? base : 64;

    float acc[8];
    {
      const float4 b0 = *(const float4*)(bd + lane * 8);
      const float4 b1 = *(const float4*)(bd + lane * 8 + 4);
      acc[0] = b0.x; acc[1] = b0.y; acc[2] = b0.z; acc[3] = b0.w;
      acc[4] = b1.x; acc[5] = b1.y; acc[6] = b1.z; acc[7] = b1.w;
    }
    for (int i = 0; i < cnt; ++i) {
      const float2 p = spair[i];
      const float* wr = WdT + (size_t)__float_as_int(p.y) * IN_DIM + lane * 8;
      const float4 w0 = *(const float4*)wr;
      const float4 w1 = *(const float4*)(wr + 4);
      acc[0] += p.x * w0.x; acc[1] += p.x * w0.y;
      acc[2] += p.x * w0.z; acc[3] += p.x * w0.w;
      acc[4] += p.x * w1.x; acc[5] += p.x * w1.y;
      acc[6] += p.x * w1.z; acc[7] += p.x * w1.w;
    }
    float* rr = recon + (size_t)row * IN_DIM + lane * 8;
    *(float4*)(rr) = make_float4(acc[0], acc[1], acc[2], acc[3]);
    *(float4*)(rr + 4) = make_float4(acc[4], acc[5], acc[6], acc[7]);
    __syncthreads();
  }
}

// ---------------------------------------------------------------------------
extern "C" void kernel_launch(void* const* d_in, const int* in_sizes, int n_in,
                              void* d_out, int out_size, void* d_ws, size_t ws_size,
                              hipStream_t stream)
{
  const float* x  = (const float*)d_in[0];
  const float* We = (const float*)d_in[1];
  const float* be = (const float*)d_in[2];
  const float* Wd = (const float*)d_in[3];
  const float* bd = (const float*)d_in[4];
  const float* pb = (const float*)d_in[5];

  const int M = in_sizes[0] / IN_DIM;   // 65536

  float* recon = (float*)d_out;                        // M x 512
  float* zs    = (float*)d_out + (size_t)M * IN_DIM;   // M x 2048 (z -> z_sparse)
  // xcHi/xcLo live in the recon region (dead until topk_decode writes it)
  unsigned short* xcHi = (unsigned short*)recon;                    // M*512 u16
  unsigned short* xcLo = xcHi + (size_t)M * IN_DIM;                 // M*512 u16

  char* ws = (char*)d_ws;
  float* WdT           = (float*)ws;                    // 4 MB
  unsigned short* WeHi = (unsigned short*)(ws + (4 << 20));   // 2 MB
  unsigned short* WeLo = (unsigned short*)(ws + (6 << 20));   // 2 MB
  int* flagCount       = (int*)(ws + (8 << 20));
  int* flagList        = flagCount + 16;

  hipMemsetAsync(flagCount, 0, 64, stream);
  transpose_wdec_kernel<<<1024, 256, 0, stream>>>(Wd, WdT);
  split_we_kernel<<<(HID * IN_DIM / 4) / 256, 256, 0, stream>>>(We, WeHi, WeLo);
  split_x_kernel<<<(M * (IN_DIM / 4)) / 256, 256, 0, stream>>>(x, bd, pb, xcHi, xcLo);
  enc_gemm_8ph_kernel<<<(M / 256) * (HID / 256), 512, 0, stream>>>(
      xcHi, xcLo, WeHi, WeLo, be, zs);
  topk_decode_kernel<<<M / 4, 256, 0, stream>>>(zs, WdT, bd, recon, flagCount, flagList);
  fixup_kernel<<<2048, 64, 0, stream>>>(x, We, be, bd, pb, WdT,
                                        flagCount, flagList, zs, recon);
}